// Round 1
// baseline (310.480 us; speedup 1.0000x reference)
//
#include <hip/hip_runtime.h>
#include <hip/hip_bf16.h>

// Dims fixed by the reference
#define BB 8
#define NN 2048
#define DF 256
#define HH 64

using bf16x8 = __attribute__((ext_vector_type(8))) short;
using f32x4  = __attribute__((ext_vector_type(4))) float;
typedef unsigned short u16;

// ---------------------------------------------------------------------------
// Kernel 1: Q/K projection. q = [f | log_eps] @ W_q (scaled by 1/8 folded into q),
// k likewise (unscaled). Output stored as split bf16 (hi, lo) per row:
// layout [bn][ hi(0..63) | lo(0..63) ]  (128 bf16 = 256 B per row).
// Split-bf16 keeps logits accurate to ~2^-17 relative.
// ---------------------------------------------------------------------------
__global__ __launch_bounds__(256) void qk_proj_kernel(
    const float* __restrict__ f, const float* __restrict__ log_eps,
    const float* __restrict__ Wq, const float* __restrict__ Wk,
    __hip_bfloat16* __restrict__ Qs, __hip_bfloat16* __restrict__ Ks)
{
    __shared__ float fs[32 * 256];           // 32 rows of f staged in LDS
    const int tid = threadIdx.x;
    const int h  = tid & 63;                 // head dim
    const int rg = tid >> 6;                 // row group (wave)
    const int row_base = blockIdx.x * 32;    // flat bn index of first row

    // stage 32 rows (coalesced float4)
    for (int it = 0; it < 8; ++it) {
        int cch = tid + it * 256;            // float4 chunk 0..2047
        int r = cch >> 6, c4 = cch & 63;
        *(float4*)&fs[r * 256 + c4 * 4] =
            *(const float4*)(f + (size_t)(row_base + r) * DF + c4 * 4);
    }
    __syncthreads();

    const int b = row_base >> 11;            // 2048 rows per batch, blocks never straddle
    const float le = log_eps[b];
    const float wq_last = Wq[DF * HH + h];
    const float wk_last = Wk[DF * HH + h];
    float q[8], k[8];
#pragma unroll
    for (int j = 0; j < 8; ++j) { q[j] = le * wq_last; k[j] = le * wk_last; }

    for (int i4 = 0; i4 < 64; ++i4) {
        float4 fv[8];
#pragma unroll
        for (int j = 0; j < 8; ++j)
            fv[j] = *(const float4*)&fs[(rg * 8 + j) * 256 + i4 * 4];
#pragma unroll
        for (int u = 0; u < 4; ++u) {
            int i = i4 * 4 + u;
            float wq = Wq[i * HH + h];
            float wk = Wk[i * HH + h];
#pragma unroll
            for (int j = 0; j < 8; ++j) {
                float fvv = (&fv[j].x)[u];
                q[j] = fmaf(fvv, wq, q[j]);
                k[j] = fmaf(fvv, wk, k[j]);
            }
        }
    }

#pragma unroll
    for (int j = 0; j < 8; ++j) {
        int bn = row_base + rg * 8 + j;
        float qv = q[j] * 0.125f;            // 1/sqrt(64) folded into q
        float kv = k[j];
        __hip_bfloat16 qh = __float2bfloat16(qv);
        __hip_bfloat16 ql = __float2bfloat16(qv - __bfloat162float(qh));
        __hip_bfloat16 kh = __float2bfloat16(kv);
        __hip_bfloat16 kl = __float2bfloat16(kv - __bfloat162float(kh));
        size_t base = (size_t)bn * 128;
        Qs[base + h]      = qh;
        Qs[base + 64 + h] = ql;
        Ks[base + h]      = kh;
        Ks[base + 64 + h] = kl;
    }
}

// ---------------------------------------------------------------------------
// Kernel 2 (fused): each block owns a 32-column strip of one batch, ALL rows.
// Phase A: p~ = exp(q.k/8) via split-bf16 MFMA (hi*hi + hi*lo + lo*hi), write
//          p~ to pi buffer, block-local colsums in LDS (no global atomics).
// Phase B: re-read own strip (L2-hot), write pi = p~/(colsum*N), accumulate
//          y[m,d] = sum_n p~*x / colsum directly (block-exclusive columns).
// No max-subtraction needed: logits ~ N(0,1), max ~ 8 -> exp safe in fp32.
// ---------------------------------------------------------------------------
__global__ __launch_bounds__(256) void attn_kernel(
    const u16* __restrict__ Qs, const u16* __restrict__ Ks,
    const float* __restrict__ x, float* __restrict__ y, float* __restrict__ pi)
{
    __shared__ float xs[NN * 3];             // 24 KB: x for this batch
    __shared__ float cs_lds[32];             // colsums for the strip
    __shared__ float yred[256 * 3];          // y reduction scratch

    const int tid   = threadIdx.x;
    const int strip = blockIdx.x;            // 0..63
    const int b     = blockIdx.y;            // 0..7
    const int m0    = strip * 32;
    const int wave  = tid >> 6;
    const int lane  = tid & 63;
    const int l15   = lane & 15;
    const int quad  = lane >> 4;

    if (tid < 32) cs_lds[tid] = 0.f;
    for (int i = tid; i < NN * 3; i += 256) xs[i] = x[(size_t)b * NN * 3 + i];
    __syncthreads();

    // B-operand fragments for the K strip: resident in registers for whole kernel.
    // B frag layout (16x16x32): n = lane&15, k = quad*8 + j
    bf16x8 bh[2][2], bl[2][2];
    {
        const u16* Kb = Ks + ((size_t)b * NN + m0) * 128;
#pragma unroll
        for (int ct = 0; ct < 2; ++ct) {
            const u16* kr = Kb + (size_t)(ct * 16 + l15) * 128;
#pragma unroll
            for (int ks = 0; ks < 2; ++ks) {
                int k0 = ks * 32 + quad * 8;
                bh[ct][ks] = *(const bf16x8*)(kr + k0);
                bl[ct][ks] = *(const bf16x8*)(kr + 64 + k0);
            }
        }
    }

    const u16* Qb = Qs + (size_t)b * NN * 128;
    float* pib = pi + (size_t)b * NN * NN + m0;
    float csacc0 = 0.f, csacc1 = 0.f;

    for (int rt = 0; rt < 16; ++rt) {
#pragma unroll
        for (int sr = 0; sr < 2; ++sr) {
            const int row0 = rt * 128 + wave * 32 + sr * 16;
            // A frags: m = lane&15 (row), k = quad*8+j — 16B contiguous global loads
            const u16* qr = Qb + (size_t)(row0 + l15) * 128;
            bf16x8 ah[2], al[2];
#pragma unroll
            for (int ks = 0; ks < 2; ++ks) {
                int k0 = ks * 32 + quad * 8;
                ah[ks] = *(const bf16x8*)(qr + k0);
                al[ks] = *(const bf16x8*)(qr + 64 + k0);
            }
#pragma unroll
            for (int ct = 0; ct < 2; ++ct) {
                f32x4 acc = {0.f, 0.f, 0.f, 0.f};
#pragma unroll
                for (int ks = 0; ks < 2; ++ks) {
                    acc = __builtin_amdgcn_mfma_f32_16x16x32_bf16(ah[ks], bh[ct][ks], acc, 0, 0, 0);
                    acc = __builtin_amdgcn_mfma_f32_16x16x32_bf16(ah[ks], bl[ct][ks], acc, 0, 0, 0);
                    acc = __builtin_amdgcn_mfma_f32_16x16x32_bf16(al[ks], bh[ct][ks], acc, 0, 0, 0);
                }
                // C/D layout: col = lane&15, row = quad*4 + reg
                float p0 = __expf(acc[0]);
                float p1 = __expf(acc[1]);
                float p2 = __expf(acc[2]);
                float p3 = __expf(acc[3]);
                float* op = pib + (size_t)(row0 + quad * 4) * NN + ct * 16 + l15;
                op[0]        = p0;
                op[NN]       = p1;
                op[2 * NN]   = p2;
                op[3 * (size_t)NN] = p3;
                float s = p0 + p1 + p2 + p3;       // 4 rows, col l15
                s += __shfl_xor(s, 16);            // + other quads
                s += __shfl_xor(s, 32);            // -> 16-row subtile colsum
                if (ct == 0) csacc0 += s; else csacc1 += s;
            }
        }
    }
    if (quad == 0) {                                // one lane per (wave, col)
        atomicAdd(&cs_lds[l15],      csacc0);
        atomicAdd(&cs_lds[16 + l15], csacc1);
    }
    __threadfence();     // make phase-A global writes visible block-wide (L1 inv)
    __syncthreads();

    // ---- Phase B: normalize + y ----
    const int c = tid & 31;                         // local column
    const int g = tid >> 5;                         // row group 0..7
    const float inv   = 1.0f / cs_lds[c];
    const float invpi = inv * (1.0f / (float)NN);
    float y0 = 0.f, y1 = 0.f, y2 = 0.f;
    float* pcol = pi + ((size_t)b * NN) * NN + m0 + c;
#pragma unroll 4
    for (int n = g; n < NN; n += 8) {
        float v = pcol[(size_t)n * NN];
        float xv0 = xs[n * 3], xv1 = xs[n * 3 + 1], xv2 = xs[n * 3 + 2];
        y0 = fmaf(v, xv0, y0);
        y1 = fmaf(v, xv1, y1);
        y2 = fmaf(v, xv2, y2);
        pcol[(size_t)n * NN] = v * invpi;
    }
    yred[tid * 3 + 0] = y0;
    yred[tid * 3 + 1] = y1;
    yred[tid * 3 + 2] = y2;
    __syncthreads();
    if (tid < 32) {
        float a0 = 0.f, a1 = 0.f, a2 = 0.f;
#pragma unroll
        for (int gg = 0; gg < 8; ++gg) {
            a0 += yred[(gg * 32 + tid) * 3 + 0];
            a1 += yred[(gg * 32 + tid) * 3 + 1];
            a2 += yred[(gg * 32 + tid) * 3 + 2];
        }
        float invc = 1.0f / cs_lds[tid];
        float* yp = y + ((size_t)b * NN + m0 + tid) * 3;
        yp[0] = a0 * invc;
        yp[1] = a1 * invc;
        yp[2] = a2 * invc;
    }
}

// ---------------------------------------------------------------------------
extern "C" void kernel_launch(void* const* d_in, const int* in_sizes, int n_in,
                              void* d_out, int out_size, void* d_ws, size_t ws_size,
                              hipStream_t stream) {
    const float* f  = (const float*)d_in[0];
    const float* x  = (const float*)d_in[1];
    const float* le = (const float*)d_in[2];
    const float* Wq = (const float*)d_in[3];
    const float* Wk = (const float*)d_in[4];

    float* y  = (float*)d_out;                       // (B, N, 3)  = 49152 floats
    float* pi = (float*)d_out + (size_t)BB * NN * 3; // (B, N, N)

    // workspace: split-bf16 Q and K, 4 MB each
    __hip_bfloat16* Qs = (__hip_bfloat16*)d_ws;
    __hip_bfloat16* Ks = Qs + (size_t)BB * NN * 128;

    qk_proj_kernel<<<dim3(BB * NN / 32), 256, 0, stream>>>(f, le, Wq, Wk, Qs, Ks);
    attn_kernel<<<dim3(64, BB), 256, 0, stream>>>((const u16*)Qs, (const u16*)Ks, x, y, pi);
}

// Round 2
// 240.211 us; speedup vs baseline: 1.2925x; 1.2925x over previous
//
#include <hip/hip_runtime.h>
#include <hip/hip_bf16.h>

// Dims fixed by the reference
#define BB 8
#define NN 2048
#define DF 256
#define HH 64

using bf16x8 = __attribute__((ext_vector_type(8))) short;
using f32x4  = __attribute__((ext_vector_type(4))) float;
typedef unsigned short u16;

// ---------------------------------------------------------------------------
// Kernel 1: Q/K projection. q = [f | log_eps] @ W_q (scale 1/8 folded into q),
// k likewise. Output split bf16 (hi, lo): [bn][ hi(0..63) | lo(0..63) ].
// v2: W chunks staged in LDS (conflict-free reads); f rows loaded with
// wave-uniform addresses (scalarizable -> s_load, no per-lane VMEM chain).
// ---------------------------------------------------------------------------
__global__ __launch_bounds__(256) void qk_proj_kernel(
    const float* __restrict__ f, const float* __restrict__ log_eps,
    const float* __restrict__ Wq, const float* __restrict__ Wk,
    __hip_bfloat16* __restrict__ Qs, __hip_bfloat16* __restrict__ Ks)
{
    __shared__ float wql[64 * 64];           // W_q chunk: [i_local][h]
    __shared__ float wkl[64 * 64];           // W_k chunk
    const int tid = threadIdx.x;
    const int h  = tid & 63;                 // head dim (lane)
    const int rg = tid >> 6;                 // wave id -> row group
    const int row_base = blockIdx.x * 32;    // flat bn of first row
    const int b = row_base >> 11;            // blocks never straddle batches

    const float le = log_eps[b];
    const float wq_last = Wq[DF * HH + h];
    const float wk_last = Wk[DF * HH + h];
    float q[8], k[8];
#pragma unroll
    for (int j = 0; j < 8; ++j) { q[j] = le * wq_last; k[j] = le * wk_last; }

    for (int kc = 0; kc < 4; ++kc) {
        __syncthreads();                     // LDS reuse guard
        // stage 64-row W chunks, coalesced float4
#pragma unroll
        for (int it = 0; it < 4; ++it) {
            int idx = (tid + it * 256) * 4;  // float offset, 0..4095
            *(float4*)&wql[idx] = *(const float4*)(Wq + kc * 4096 + idx);
            *(float4*)&wkl[idx] = *(const float4*)(Wk + kc * 4096 + idx);
        }
        __syncthreads();

        const float* fb = f + (size_t)(row_base + rg * 8) * DF + kc * 64;
#pragma unroll 4
        for (int i4 = 0; i4 < 16; ++i4) {
            float4 fv[8];                    // wave-uniform loads (8 rows)
#pragma unroll
            for (int j = 0; j < 8; ++j)
                fv[j] = *(const float4*)(fb + (size_t)j * DF + i4 * 4);
#pragma unroll
            for (int u = 0; u < 4; ++u) {
                float wq = wql[(i4 * 4 + u) * 64 + h];
                float wk = wkl[(i4 * 4 + u) * 64 + h];
#pragma unroll
                for (int j = 0; j < 8; ++j) {
                    float fvv = (&fv[j].x)[u];
                    q[j] = fmaf(fvv, wq, q[j]);
                    k[j] = fmaf(fvv, wk, k[j]);
                }
            }
        }
    }

#pragma unroll
    for (int j = 0; j < 8; ++j) {
        int bn = row_base + rg * 8 + j;
        float qv = q[j] * 0.125f;            // 1/sqrt(64) folded into q
        float kv = k[j];
        __hip_bfloat16 qh = __float2bfloat16(qv);
        __hip_bfloat16 ql = __float2bfloat16(qv - __bfloat162float(qh));
        __hip_bfloat16 kh = __float2bfloat16(kv);
        __hip_bfloat16 kl = __float2bfloat16(kv - __bfloat162float(kh));
        size_t base = (size_t)bn * 128;
        Qs[base + h]      = qh;
        Qs[base + 64 + h] = ql;
        Ks[base + h]      = kh;
        Ks[base + 64 + h] = kl;
    }
}

// ---------------------------------------------------------------------------
// Kernel 2: each block owns a 32-column strip of one batch, ALL rows.
// Pass 1: p~ = exp(q.k/8) via split-bf16 MFMA, block-local colsums in LDS.
//         NO global stores.
// Pass 2: recompute MFMA, write pi = p~*inv/N directly (single write of the
//         pi buffer), accumulate y[m,d] = sum_n p~*inv*x in registers.
// The recompute trades 2x MFMA (3% util) for eliminating 134 MB write +
// 134 MB HBM read-back of unnormalized p~.
// ---------------------------------------------------------------------------
__global__ __launch_bounds__(256) void attn_kernel(
    const u16* __restrict__ Qs, const u16* __restrict__ Ks,
    const float* __restrict__ x, float* __restrict__ y, float* __restrict__ pi)
{
    __shared__ float xs[NN * 3];             // 24 KB: x for this batch
    __shared__ float cs_lds[32];             // strip colsums
    __shared__ float yred[4 * 2 * 16 * 3];   // [wave][ct][col16][d]

    const int tid   = threadIdx.x;
    const int strip = blockIdx.x;            // 0..63
    const int b     = blockIdx.y;            // 0..7
    const int m0    = strip * 32;
    const int wave  = tid >> 6;
    const int lane  = tid & 63;
    const int l15   = lane & 15;
    const int quad  = lane >> 4;

    if (tid < 32) cs_lds[tid] = 0.f;
    for (int i = tid; i < NN * 3; i += 256) xs[i] = x[(size_t)b * NN * 3 + i];
    __syncthreads();

    // B-frags for the K strip, resident all kernel. B layout: n=lane&15, k=quad*8+j
    bf16x8 bh[2][2], bl[2][2];
    {
        const u16* Kb = Ks + ((size_t)b * NN + m0) * 128;
#pragma unroll
        for (int ct = 0; ct < 2; ++ct) {
            const u16* kr = Kb + (size_t)(ct * 16 + l15) * 128;
#pragma unroll
            for (int ks = 0; ks < 2; ++ks) {
                int k0 = ks * 32 + quad * 8;
                bh[ct][ks] = *(const bf16x8*)(kr + k0);
                bl[ct][ks] = *(const bf16x8*)(kr + 64 + k0);
            }
        }
    }

    const u16* Qb = Qs + (size_t)b * NN * 128;
    float csacc0 = 0.f, csacc1 = 0.f;

    // ---- Pass 1: colsums only ----
    for (int rt = 0; rt < 16; ++rt) {
#pragma unroll
        for (int sr = 0; sr < 2; ++sr) {
            const int row0 = rt * 128 + wave * 32 + sr * 16;
            const u16* qr = Qb + (size_t)(row0 + l15) * 128;
            bf16x8 ah[2], al[2];
#pragma unroll
            for (int ks = 0; ks < 2; ++ks) {
                int k0 = ks * 32 + quad * 8;
                ah[ks] = *(const bf16x8*)(qr + k0);
                al[ks] = *(const bf16x8*)(qr + 64 + k0);
            }
#pragma unroll
            for (int ct = 0; ct < 2; ++ct) {
                f32x4 acc = {0.f, 0.f, 0.f, 0.f};
#pragma unroll
                for (int ks = 0; ks < 2; ++ks) {
                    acc = __builtin_amdgcn_mfma_f32_16x16x32_bf16(ah[ks], bh[ct][ks], acc, 0, 0, 0);
                    acc = __builtin_amdgcn_mfma_f32_16x16x32_bf16(ah[ks], bl[ct][ks], acc, 0, 0, 0);
                    acc = __builtin_amdgcn_mfma_f32_16x16x32_bf16(al[ks], bh[ct][ks], acc, 0, 0, 0);
                }
                float s = __expf(acc[0]) + __expf(acc[1]) + __expf(acc[2]) + __expf(acc[3]);
                s += __shfl_xor(s, 16);
                s += __shfl_xor(s, 32);
                if (ct == 0) csacc0 += s; else csacc1 += s;
            }
        }
    }
    if (quad == 0) {
        atomicAdd(&cs_lds[l15],      csacc0);
        atomicAdd(&cs_lds[16 + l15], csacc1);
    }
    __syncthreads();

    const float invc0 = 1.0f / cs_lds[l15];
    const float invc1 = 1.0f / cs_lds[16 + l15];
    const float invN  = 1.0f / (float)NN;
    float* pib = pi + (size_t)b * NN * NN + m0;
    float yacc[2][3] = {{0.f, 0.f, 0.f}, {0.f, 0.f, 0.f}};

    // ---- Pass 2: recompute, write pi, accumulate y ----
    for (int rt = 0; rt < 16; ++rt) {
#pragma unroll
        for (int sr = 0; sr < 2; ++sr) {
            const int row0 = rt * 128 + wave * 32 + sr * 16;
            const u16* qr = Qb + (size_t)(row0 + l15) * 128;
            bf16x8 ah[2], al[2];
#pragma unroll
            for (int ks = 0; ks < 2; ++ks) {
                int k0 = ks * 32 + quad * 8;
                ah[ks] = *(const bf16x8*)(qr + k0);
                al[ks] = *(const bf16x8*)(qr + 64 + k0);
            }
            float xv[4][3];                  // x rows for this lane's quad
#pragma unroll
            for (int r = 0; r < 4; ++r) {
                int row = row0 + quad * 4 + r;
                xv[r][0] = xs[row * 3 + 0];
                xv[r][1] = xs[row * 3 + 1];
                xv[r][2] = xs[row * 3 + 2];
            }
#pragma unroll
            for (int ct = 0; ct < 2; ++ct) {
                f32x4 acc = {0.f, 0.f, 0.f, 0.f};
#pragma unroll
                for (int ks = 0; ks < 2; ++ks) {
                    acc = __builtin_amdgcn_mfma_f32_16x16x32_bf16(ah[ks], bh[ct][ks], acc, 0, 0, 0);
                    acc = __builtin_amdgcn_mfma_f32_16x16x32_bf16(ah[ks], bl[ct][ks], acc, 0, 0, 0);
                    acc = __builtin_amdgcn_mfma_f32_16x16x32_bf16(al[ks], bh[ct][ks], acc, 0, 0, 0);
                }
                const float iv = (ct == 0) ? invc0 : invc1;
                float* op = pib + (size_t)(row0 + quad * 4) * NN + ct * 16 + l15;
#pragma unroll
                for (int r = 0; r < 4; ++r) {
                    float v = __expf(acc[r]) * iv;     // normalized softmax
                    op[(size_t)r * NN] = v * invN;     // pi
                    yacc[ct][0] = fmaf(v, xv[r][0], yacc[ct][0]);
                    yacc[ct][1] = fmaf(v, xv[r][1], yacc[ct][1]);
                    yacc[ct][2] = fmaf(v, xv[r][2], yacc[ct][2]);
                }
            }
        }
    }

    // reduce y over quads (rows are partitioned across quads), then waves
#pragma unroll
    for (int ct = 0; ct < 2; ++ct)
#pragma unroll
        for (int d = 0; d < 3; ++d) {
            yacc[ct][d] += __shfl_xor(yacc[ct][d], 16);
            yacc[ct][d] += __shfl_xor(yacc[ct][d], 32);
        }
    if (quad == 0) {
#pragma unroll
        for (int ct = 0; ct < 2; ++ct)
#pragma unroll
            for (int d = 0; d < 3; ++d)
                yred[((wave * 2 + ct) * 16 + l15) * 3 + d] = yacc[ct][d];
    }
    __syncthreads();
    if (tid < 96) {                          // 32 cols x 3 dims
        int c = tid / 3, d = tid - c * 3;    // c: local col 0..31
        int ct = c >> 4, cl = c & 15;
        float s = 0.f;
#pragma unroll
        for (int w = 0; w < 4; ++w)
            s += yred[((w * 2 + ct) * 16 + cl) * 3 + d];
        y[((size_t)b * NN + m0 + c) * 3 + d] = s;
    }
}

// ---------------------------------------------------------------------------
extern "C" void kernel_launch(void* const* d_in, const int* in_sizes, int n_in,
                              void* d_out, int out_size, void* d_ws, size_t ws_size,
                              hipStream_t stream) {
    const float* f  = (const float*)d_in[0];
    const float* x  = (const float*)d_in[1];
    const float* le = (const float*)d_in[2];
    const float* Wq = (const float*)d_in[3];
    const float* Wk = (const float*)d_in[4];

    float* y  = (float*)d_out;                       // (B, N, 3)
    float* pi = (float*)d_out + (size_t)BB * NN * 3; // (B, N, N)

    __hip_bfloat16* Qs = (__hip_bfloat16*)d_ws;      // split-bf16 Q, K
    __hip_bfloat16* Ks = Qs + (size_t)BB * NN * 128;

    qk_proj_kernel<<<dim3(BB * NN / 32), 256, 0, stream>>>(f, le, Wq, Wk, Qs, Ks);
    attn_kernel<<<dim3(64, BB), 256, 0, stream>>>((const u16*)Qs, (const u16*)Ks, x, y, pi);
}